// Round 8
// baseline (1730.220 us; speedup 1.0000x reference)
//
#include <hip/hip_runtime.h>
#include <cstddef>
#include <cstdint>

#define Tn 512
#define Bn 512

typedef float f32x2 __attribute__((ext_vector_type(2)));

__device__ __forceinline__ float rlane(float v, int lane) {
    return __uint_as_float((unsigned)__builtin_amdgcn_readlane((int)__float_as_uint(v), lane));
}
__device__ __forceinline__ float sigm(float x) { return 1.0f / (1.0f + __expf(-x)); }
// tanh(x) = 1 - 2/(1+e^{2x}); inf-safe at both ends
__device__ __forceinline__ float tanhf_(float x) { return 1.0f - 2.0f / (1.0f + __expf(2.0f * x)); }

// LDS-visibility barrier WITHOUT the __syncthreads vmcnt(0) drain.
#define BAR_LGKM() asm volatile("s_waitcnt lgkmcnt(0)\n\ts_barrier" ::: "memory")
// Pin a value into arch-VGPR class (holds when live set <= ~200 regs — R5 vs R7).
#define PIN(v) asm volatile("" : "+v"(v))

// Gate-pair dot: G += sum_k rlane(SRC,k) * w2[k]. 64 rlane + 64 pk_fma,
// two accumulators for dep-chain ILP. w2[64] f32x2 = 128 VGPRs.
#define DOTP(SRC, G)                                                         \
    do {                                                                     \
        f32x2 _qa = {0.f, 0.f}, _qb = {0.f, 0.f};                            \
        _Pragma("unroll")                                                    \
        for (int _k = 0; _k < 64; _k += 2) {                                 \
            const float _v0 = rlane((SRC), _k);                              \
            const float _v1 = rlane((SRC), _k + 1);                          \
            _qa = __builtin_elementwise_fma((f32x2){_v0, _v0}, w2[_k], _qa); \
            _qb = __builtin_elementwise_fma((f32x2){_v1, _v1}, w2[_k + 1], _qb); \
        }                                                                    \
        (G) += _qa + _qb;                                                    \
    } while (0)

// Given own pair P (this wave's 2 gates) and other pair O, gp-uniform select
// and activate. gp==0: P={i,f} O={g,o}; gp==1: P={g,o} O={i,f}.
#define ACT_PAIR(P, O, C, H)                                   \
    do {                                                       \
        const float _gi = gp ? (O).x : (P).x;                  \
        const float _gf = gp ? (O).y : (P).y;                  \
        const float _gg = gp ? (P).x : (O).x;                  \
        const float _go = gp ? (P).y : (O).y;                  \
        (C) = sigm(_gf) * (C) + sigm(_gi) * tanhf_(_gg);       \
        (H) = sigm(_go) * tanhf_(C);                           \
    } while (0)

// ---------------------------------------------------------------------------
// Layer 0 (IN=1). Block = 128 thr = 2 gate-split waves, TWO batch elements of
// one direction. Wave gp owns gates {i,f} (gp=0) or {g,o} (gp=1) with FULL
// K=64: weights 64 f32x2 = 128 regs, live ~170 < 256 arch ceiling -> pure
// VGPR. Per step/elem: 64 rlane + 64 pk_fma; one f32x2 LDS exchange + one
// lgkm-only barrier; both waves redundantly activate (bit-identical h).
// 512 blocks (b-pair x dir) x 2 waves = 4 waves/CU.
// ---------------------------------------------------------------------------
__global__ __launch_bounds__(128, 1) void k_lstm_l0(
    const float* __restrict__ x,
    const float* __restrict__ wih_f, const float* __restrict__ whh_f,
    const float* __restrict__ bih_f, const float* __restrict__ bhh_f,
    const float* __restrict__ wih_r, const float* __restrict__ whh_r,
    const float* __restrict__ bih_r, const float* __restrict__ bhh_r,
    float* __restrict__ h0out)
{
    const int tid = threadIdx.x;
    const int gp  = tid >> 6;        // gate pair: 0 -> {i,f}, 1 -> {g,o}
    const int j   = tid & 63;        // hidden unit
    const int dir = blockIdx.x & 1;
    const int b0  = (blockIdx.x >> 1) * 2;
    const int b1  = b0 + 1;

    const float* __restrict__ wih = dir ? wih_r : wih_f;
    const float* __restrict__ whh = dir ? whh_r : whh_f;
    const float* __restrict__ bih = dir ? bih_r : bih_f;
    const float* __restrict__ bhh = dir ? bhh_r : bhh_f;

    __shared__ float xs[2][Tn];          // 4 KB
    __shared__ f32x2 pp[2][2][2][64];    // [buf][gp][e][j], 4 KB

    #pragma unroll
    for (int i = 0; i < Tn / 128; ++i) {
        xs[0][i * 128 + tid] = x[(size_t)b0 * Tn + i * 128 + tid];
        xs[1][i * 128 + tid] = x[(size_t)b1 * Tn + i * 128 + tid];
    }

    const int r0 = gp * 128 + j;         // row of first gate in pair
    const int r1 = gp * 128 + 64 + j;    // row of second gate
    f32x2 w2[64];
    #pragma unroll
    for (int k = 0; k < 64; ++k) {
        w2[k] = (f32x2){whh[(size_t)r0 * 64 + k], whh[(size_t)r1 * 64 + k]};
        PIN(w2[k]);
    }
    const f32x2 wx   = {wih[r0], wih[r1]};
    const f32x2 bias = {bih[r0] + bhh[r0], bih[r1] + bhh[r1]};

    __syncthreads();   // once: xs visible (pre-loop drain harmless)

    float hA = 0.f, cA = 0.f, hB = 0.f, cB = 0.f;
    float* __restrict__ outA = h0out + (size_t)b0 * Tn * 128 + dir * 64 + j;
    float* __restrict__ outB = h0out + (size_t)b1 * Tn * 128 + dir * 64 + j;

    for (int s = 0; s < Tn; ++s) {
        const int t  = dir ? (Tn - 1 - s) : s;
        const int bf = s & 1;
        const float xtA = xs[0][t];      // uniform-addr LDS broadcast
        const float xtB = xs[1][t];

        f32x2 pA = __builtin_elementwise_fma((f32x2){xtA, xtA}, wx, bias);
        DOTP(hA, pA);
        f32x2 pB = __builtin_elementwise_fma((f32x2){xtB, xtB}, wx, bias);
        DOTP(hB, pB);
        pp[bf][gp][0][j] = pA;
        pp[bf][gp][1][j] = pB;
        BAR_LGKM();
        const f32x2 oA = pp[bf][1 ^ gp][0][j];
        const f32x2 oB = pp[bf][1 ^ gp][1][j];
        ACT_PAIR(pA, oA, cA, hA);
        ACT_PAIR(pB, oB, cB, hB);
        if (gp == 0) outA[(size_t)t * 128] = hA;   // wave-uniform; never drained
        else         outB[(size_t)t * 128] = hB;
    }
}

// ---------------------------------------------------------------------------
// XG1 precompute (layer-1 fwd input GEMM, throughput-bound, no recurrence):
// XG1p[b][t][gp][j] (f32x2) = bias + sum_k x1[b][t][k] * wih[gate rows].
// Block = 256 thr = 4 waves (gp x K-half), 32 timesteps of one b per block.
// Weights/wave = 64 f32x2 = 128 regs. K-half partials combined through LDS
// once per 4-step chunk (2 barriers per chunk, amortized).
// ---------------------------------------------------------------------------
__global__ __launch_bounds__(256, 1) void k_xg1(
    const float* __restrict__ h0in,
    const float* __restrict__ wih,
    const float* __restrict__ bih, const float* __restrict__ bhh,
    f32x2* __restrict__ xg)
{
    const int tid = threadIdx.x;
    const int wv  = tid >> 6;        // 0..3
    const int gp  = wv & 1;
    const int kh  = wv >> 1;
    const int j   = tid & 63;
    const int b   = blockIdx.x >> 4;
    const int t0  = (blockIdx.x & 15) * 32;

    __shared__ f32x2 ppc[4][2][2][64];   // [ct][gp][kh][j], 8 KB

    const int r0 = gp * 128 + j;
    const int r1 = gp * 128 + 64 + j;
    f32x2 w2[64];
    #pragma unroll
    for (int k = 0; k < 64; ++k) {
        w2[k] = (f32x2){wih[(size_t)r0 * 128 + kh * 64 + k],
                        wih[(size_t)r1 * 128 + kh * 64 + k]};
        PIN(w2[k]);
    }
    f32x2 biasP[2];
    biasP[0] = (f32x2){bih[j] + bhh[j],             bih[64 + j] + bhh[64 + j]};
    biasP[1] = (f32x2){bih[128 + j] + bhh[128 + j], bih[192 + j] + bhh[192 + j]};

    // lane j = k-index within this wave's K-half
    const float* __restrict__ xbase = h0in + ((size_t)b * Tn + t0) * 128 + kh * 64 + j;

    float xq0 = xbase[0 * 128], xq1 = xbase[1 * 128];
    float xq2 = xbase[2 * 128], xq3 = xbase[3 * 128];

    for (int ch = 0; ch < 8; ++ch) {
        float xn0 = 0.f, xn1 = 0.f, xn2 = 0.f, xn3 = 0.f;
        if (ch < 7) {        // prefetch next chunk (in flight across barriers)
            const float* nb = xbase + (size_t)(ch + 1) * 4 * 128;
            xn0 = nb[0]; xn1 = nb[128]; xn2 = nb[256]; xn3 = nb[384];
        }
        { f32x2 g = {0.f, 0.f}; DOTP(xq0, g); ppc[0][gp][kh][j] = g; }
        { f32x2 g = {0.f, 0.f}; DOTP(xq1, g); ppc[1][gp][kh][j] = g; }
        { f32x2 g = {0.f, 0.f}; DOTP(xq2, g); ppc[2][gp][kh][j] = g; }
        { f32x2 g = {0.f, 0.f}; DOTP(xq3, g); ppc[3][gp][kh][j] = g; }
        BAR_LGKM();
        {   // wave wv combines timestep ct == wv (perfect 4-way split)
            const int t = t0 + ch * 4 + wv;
            const f32x2 s0 = ppc[wv][0][0][j] + ppc[wv][0][1][j] + biasP[0];
            const f32x2 s1 = ppc[wv][1][0][j] + ppc[wv][1][1][j] + biasP[1];
            xg[((size_t)b * Tn + t) * 128 +      j] = s0;   // gp=0 pair
            xg[((size_t)b * Tn + t) * 128 + 64 + j] = s1;   // gp=1 pair
        }
        BAR_LGKM();          // protect ppc from next chunk's writes
        xq0 = xn0; xq1 = xn1; xq2 = xn2; xq3 = xn3;
    }
}

// ---------------------------------------------------------------------------
// Layer-1 forward scan over precomputed XG1 (recurrent K=64 only).
// Same 2-wave gate-split template as k_lstm_l0; XG1 pair loads are 2-deep
// register-prefetched (lgkm-only barriers never drain vmcnt).
// 256 blocks x 2 waves; weights 128 regs, live ~175.
// ---------------------------------------------------------------------------
__global__ __launch_bounds__(128, 1) void k_scan1(
    const f32x2* __restrict__ xg,
    const float* __restrict__ whh,
    float* __restrict__ h1last)
{
    const int tid = threadIdx.x;
    const int gp  = tid >> 6;
    const int j   = tid & 63;
    const int b0  = blockIdx.x * 2;
    const int b1  = b0 + 1;

    __shared__ f32x2 pp[2][2][2][64];    // [buf][gp][e][j], 4 KB

    const int r0 = gp * 128 + j;
    const int r1 = gp * 128 + 64 + j;
    f32x2 w2[64];
    #pragma unroll
    for (int k = 0; k < 64; ++k) {
        w2[k] = (f32x2){whh[(size_t)r0 * 64 + k], whh[(size_t)r1 * 64 + k]};
        PIN(w2[k]);
    }

    // XG1p element index: (b*Tn + t)*128 + gp*64 + j  (f32x2 units)
    const f32x2* __restrict__ xgA = xg + (size_t)b0 * Tn * 128 + gp * 64 + j;
    const f32x2* __restrict__ xgB = xg + (size_t)b1 * Tn * 128 + gp * 64 + j;

    f32x2 qA0 = xgA[0], qA1 = xgA[128];
    f32x2 qB0 = xgB[0], qB1 = xgB[128];
    float hA = 0.f, cA = 0.f, hB = 0.f, cB = 0.f;

    for (int t = 0; t < Tn; ++t) {
        const int bf = t & 1;
        const size_t tp = (size_t)((t + 2 < Tn) ? t + 2 : Tn - 1) * 128;
        const f32x2 qA2 = xgA[tp];       // prefetch; floats across barriers
        const f32x2 qB2 = xgB[tp];

        f32x2 pA = qA0;
        DOTP(hA, pA);
        f32x2 pB = qB0;
        DOTP(hB, pB);
        pp[bf][gp][0][j] = pA;
        pp[bf][gp][1][j] = pB;
        BAR_LGKM();
        const f32x2 oA = pp[bf][1 ^ gp][0][j];
        const f32x2 oB = pp[bf][1 ^ gp][1][j];
        ACT_PAIR(pA, oA, cA, hA);
        ACT_PAIR(pB, oB, cB, hB);
        qA0 = qA1; qA1 = qA2;
        qB0 = qB1; qB1 = qB2;
    }
    if (gp == 0) h1last[(size_t)b0 * 64 + j] = hA;
    else         h1last[(size_t)b1 * 64 + j] = hB;
}

// ---------------------------------------------------------------------------
// FALLBACK layer-1 fwd (R7 fused 3-wave version) for small ws_size.
// ---------------------------------------------------------------------------
#define DOT64(S)                                                              \
    do {                                                                      \
        f32x2 aa = {0.f, 0.f}, ab = {0.f, 0.f};                               \
        f32x2 ba = {0.f, 0.f}, bb = {0.f, 0.f};                               \
        _Pragma("unroll")                                                     \
        for (int k = 0; k < 64; k += 2) {                                     \
            const float v0 = rlane((S), k);                                   \
            const float v1 = rlane((S), k + 1);                               \
            aa = __builtin_elementwise_fma((f32x2){v0, v0}, wp01[k], aa);     \
            ba = __builtin_elementwise_fma((f32x2){v0, v0}, wp23[k], ba);     \
            ab = __builtin_elementwise_fma((f32x2){v1, v1}, wp01[k + 1], ab); \
            bb = __builtin_elementwise_fma((f32x2){v1, v1}, wp23[k + 1], bb); \
        }                                                                     \
        g01 = aa + ab;                                                        \
        g23 = ba + bb;                                                        \
    } while (0)

__global__ __launch_bounds__(192, 1) void k_lstm_l1f_fused(
    const float* __restrict__ h0in,
    const float* __restrict__ wih, const float* __restrict__ whh,
    const float* __restrict__ bih, const float* __restrict__ bhh,
    float* __restrict__ h1last)
{
    const int tid = threadIdx.x;
    const int wv  = tid >> 6;
    const int j   = tid & 63;
    const int b   = blockIdx.x;

    __shared__ float4 part[2][2][64];

    const float *w0b, *w1b, *w2b, *w3b;
    if (wv == 2) {
        w0b = whh + (size_t)(  0 + j) * 64;
        w1b = whh + (size_t)( 64 + j) * 64;
        w2b = whh + (size_t)(128 + j) * 64;
        w3b = whh + (size_t)(192 + j) * 64;
    } else {
        const int o = wv * 64;
        w0b = wih + (size_t)(  0 + j) * 128 + o;
        w1b = wih + (size_t)( 64 + j) * 128 + o;
        w2b = wih + (size_t)(128 + j) * 128 + o;
        w3b = wih + (size_t)(192 + j) * 128 + o;
    }
    f32x2 wp01[64], wp23[64];
    #pragma unroll
    for (int k = 0; k < 64; ++k) {
        wp01[k] = (f32x2){w0b[k], w1b[k]};
        wp23[k] = (f32x2){w2b[k], w3b[k]};
    }
    const f32x2 bias01 = {bih[j] + bhh[j],             bih[64 + j] + bhh[64 + j]};
    const f32x2 bias23 = {bih[128 + j] + bhh[128 + j], bih[192 + j] + bhh[192 + j]};

    const float* __restrict__ xrow = h0in + (size_t)b * Tn * 128 + (wv & 1) * 64 + j;
    float s0 = 0.f, s1 = 0.f;
    if (wv < 2) { s0 = xrow[0]; s1 = xrow[128]; }
    float h = 0.f, c = 0.f;

    for (int t = 0; t < Tn; ++t) {
        const int bf = t & 1;
        float s2 = 0.f;
        if (wv < 2) {
            const int tp = (t + 2 < Tn) ? t + 2 : Tn - 1;
            s2 = xrow[(size_t)tp * 128];
        }
        f32x2 g01, g23;
        if (wv == 0)      { DOT64(s0); part[bf][0][j] = make_float4(g01.x, g01.y, g23.x, g23.y); }
        else if (wv == 1) { DOT64(s0); part[bf][1][j] = make_float4(g01.x, g01.y, g23.x, g23.y); }
        else              { DOT64(h); }
        BAR_LGKM();
        if (wv == 2) {
            const float4 q0 = part[bf][0][j];
            const float4 q1 = part[bf][1][j];
            g01 = g01 + (f32x2){q0.x, q0.y} + (f32x2){q1.x, q1.y} + bias01;
            g23 = g23 + (f32x2){q0.z, q0.w} + (f32x2){q1.z, q1.w} + bias23;
            const float gi = g01.x, gf = g01.y, gg = g23.x, go = g23.y;
            c = sigm(gf) * c + sigm(gi) * tanhf_(gg);
            h = sigm(go) * tanhf_(c);
        }
        s0 = s1; s1 = s2;
    }
    if (wv == 2) h1last[(size_t)b * 64 + j] = h;
}

// ---------------------------------------------------------------------------
// Layer-1 backward direction collapses to ONE step at t=T-1 (zero init state),
// then the final FC. One wave per batch element.
// ---------------------------------------------------------------------------
__global__ __launch_bounds__(64, 1) void k_l1r_fc(
    const float* __restrict__ h0in,
    const float* __restrict__ wihr,
    const float* __restrict__ bihr, const float* __restrict__ bhhr,
    const float* __restrict__ h1last,
    const float* __restrict__ fcw, const float* __restrict__ fcb,
    float* __restrict__ out)
{
    const int b = blockIdx.x;
    const int j = threadIdx.x;
    const float* __restrict__ xrow = h0in + ((size_t)b * Tn + (Tn - 1)) * 128;
    const float x1a = xrow[j];
    const float x1b = xrow[64 + j];
    float acc[4];
    #pragma unroll
    for (int g = 0; g < 4; ++g) {
        const int r = g * 64 + j;
        float a = bihr[r] + bhhr[r];
        const float* __restrict__ wr = wihr + (size_t)r * 128;
        #pragma unroll
        for (int d4 = 0; d4 < 16; ++d4) {
            const float4 w4 = *reinterpret_cast<const float4*>(&wr[d4 * 4]);
            a = fmaf(rlane(x1a, d4 * 4 + 0), w4.x, a);
            a = fmaf(rlane(x1a, d4 * 4 + 1), w4.y, a);
            a = fmaf(rlane(x1a, d4 * 4 + 2), w4.z, a);
            a = fmaf(rlane(x1a, d4 * 4 + 3), w4.w, a);
        }
        #pragma unroll
        for (int d4 = 0; d4 < 16; ++d4) {
            const float4 w4 = *reinterpret_cast<const float4*>(&wr[64 + d4 * 4]);
            a = fmaf(rlane(x1b, d4 * 4 + 0), w4.x, a);
            a = fmaf(rlane(x1b, d4 * 4 + 1), w4.y, a);
            a = fmaf(rlane(x1b, d4 * 4 + 2), w4.z, a);
            a = fmaf(rlane(x1b, d4 * 4 + 3), w4.w, a);
        }
        acc[g] = a;
    }
    const float cr = sigm(acc[0]) * tanhf_(acc[2]);
    const float hr = sigm(acc[3]) * tanhf_(cr);
    float v = h1last[(size_t)b * 64 + j] * fcw[j] + hr * fcw[64 + j];
    #pragma unroll
    for (int off = 32; off > 0; off >>= 1) v += __shfl_xor(v, off, 64);
    if (j == 0) out[b] = v + fcb[0];
}

// ---------------------------------------------------------------------------
extern "C" void kernel_launch(void* const* d_in, const int* in_sizes, int n_in,
                              void* d_out, int out_size, void* d_ws, size_t ws_size,
                              hipStream_t stream)
{
    const float* x       = (const float*)d_in[0];
    const float* wih_l0  = (const float*)d_in[1];
    const float* whh_l0  = (const float*)d_in[2];
    const float* bih_l0  = (const float*)d_in[3];
    const float* bhh_l0  = (const float*)d_in[4];
    const float* wih_l0r = (const float*)d_in[5];
    const float* whh_l0r = (const float*)d_in[6];
    const float* bih_l0r = (const float*)d_in[7];
    const float* bhh_l0r = (const float*)d_in[8];
    const float* wih_l1  = (const float*)d_in[9];
    const float* whh_l1  = (const float*)d_in[10];
    const float* bih_l1  = (const float*)d_in[11];
    const float* bhh_l1  = (const float*)d_in[12];
    const float* wih_l1r = (const float*)d_in[13];
    const float* whh_l1r = (const float*)d_in[14];
    const float* bih_l1r = (const float*)d_in[15];
    const float* bhh_l1r = (const float*)d_in[16];
    const float* fcw     = (const float*)d_in[17];
    const float* fcb     = (const float*)d_in[18];
    (void)whh_l1r; (void)in_sizes; (void)n_in; (void)out_size;

    // ws layout: h0 [512][512][128] f32 (134.2 MB) | h1last [512][64] f32 |
    //            XG1p [512][512][128] f32x2 (268.4 MB, path A only)
    float* h0     = (float*)d_ws;
    float* h1last = h0 + (size_t)Bn * Tn * 128;
    f32x2* xg1    = (f32x2*)(h1last + (size_t)Bn * 64);
    const size_t need = (size_t)Bn * Tn * 128 * 4   // h0
                      + (size_t)Bn * 64 * 4         // h1last
                      + (size_t)Bn * Tn * 128 * 8;  // XG1p

    k_lstm_l0<<<dim3(Bn), dim3(128), 0, stream>>>(
        x, wih_l0, whh_l0, bih_l0, bhh_l0,
        wih_l0r, whh_l0r, bih_l0r, bhh_l0r, h0);

    if (ws_size >= need) {
        k_xg1<<<dim3(Bn * 16), dim3(256), 0, stream>>>(
            h0, wih_l1, bih_l1, bhh_l1, xg1);
        k_scan1<<<dim3(Bn / 2), dim3(128), 0, stream>>>(
            xg1, whh_l1, h1last);
    } else {
        k_lstm_l1f_fused<<<dim3(Bn), dim3(192), 0, stream>>>(
            h0, wih_l1, whh_l1, bih_l1, bhh_l1, h1last);
    }
    k_l1r_fc<<<dim3(Bn), dim3(64), 0, stream>>>(
        h0, wih_l1r, bih_l1r, bhh_l1r, h1last, fcw, fcb, (float*)d_out);
}

// Round 9
// 1277.997 us; speedup vs baseline: 1.3539x; 1.3539x over previous
//
#include <hip/hip_runtime.h>
#include <cstddef>
#include <cstdint>

#define Tn 512
#define Bn 512

typedef float f32x2 __attribute__((ext_vector_type(2)));

__device__ __forceinline__ float rlane(float v, int lane) {
    return __uint_as_float((unsigned)__builtin_amdgcn_readlane((int)__float_as_uint(v), lane));
}
__device__ __forceinline__ float sigm(float x) { return 1.0f / (1.0f + __expf(-x)); }
// tanh(x) = 1 - 2/(1+e^{2x}); inf-safe at both ends
__device__ __forceinline__ float tanhf_(float x) { return 1.0f - 2.0f / (1.0f + __expf(2.0f * x)); }

// LDS-visibility barrier WITHOUT the __syncthreads vmcnt(0) drain.
#define BAR_LGKM() asm volatile("s_waitcnt lgkmcnt(0)\n\ts_barrier" ::: "memory")

// Gate-pair dot: G += sum_k rlane(SRC,k) * w2[k]. 64 rlane + 64 pk_fma,
// two accumulators for dep-chain ILP.
#define DOTP(SRC, G)                                                         \
    do {                                                                     \
        f32x2 _qa = {0.f, 0.f}, _qb = {0.f, 0.f};                            \
        _Pragma("unroll")                                                    \
        for (int _k = 0; _k < 64; _k += 2) {                                 \
            const float _v0 = rlane((SRC), _k);                              \
            const float _v1 = rlane((SRC), _k + 1);                          \
            _qa = __builtin_elementwise_fma((f32x2){_v0, _v0}, w2[_k], _qa); \
            _qb = __builtin_elementwise_fma((f32x2){_v1, _v1}, w2[_k + 1], _qb); \
        }                                                                    \
        (G) += _qa + _qb;                                                    \
    } while (0)

// Own pair P (this wave's 2 gates) + other pair O -> activate (gp-uniform).
// gp==0: P={i,f} O={g,o}; gp==1: P={g,o} O={i,f}. Identical arithmetic order
// in both waves -> bit-identical h.
#define ACT_PAIR(P, O, C, H)                                   \
    do {                                                       \
        const float _gi = gp ? (O).x : (P).x;                  \
        const float _gf = gp ? (O).y : (P).y;                  \
        const float _gg = gp ? (P).x : (O).x;                  \
        const float _go = gp ? (P).y : (O).y;                  \
        (C) = sigm(_gf) * (C) + sigm(_gi) * tanhf_(_gg);       \
        (H) = sigm(_go) * tanhf_(C);                           \
    } while (0)

// ---------------------------------------------------------------------------
// Layer 0 (IN=1). ONE (b,dir) chain per 128-thr block = 2 gate-split waves.
// Grid 1024 -> 4 blocks/CU -> 8 waves/CU -> 2 waves/SIMD, and the 2 waves on
// a SIMD belong to DIFFERENT chains (different blocks) -> independent streams
// overlap each other's stalls (the Round-3 l1f mechanism, applied to l0).
// Per wave/step: 64 rlane + 64 pk_fma + 1 f32x2 LDS exchange + 1 lgkm-only
// barrier + redundant activation. Weights 64 f32x2 = 128 regs.
// ---------------------------------------------------------------------------
__global__ __launch_bounds__(128, 2) void k_lstm_l0(
    const float* __restrict__ x,
    const float* __restrict__ wih_f, const float* __restrict__ whh_f,
    const float* __restrict__ bih_f, const float* __restrict__ bhh_f,
    const float* __restrict__ wih_r, const float* __restrict__ whh_r,
    const float* __restrict__ bih_r, const float* __restrict__ bhh_r,
    float* __restrict__ h0out)
{
    const int tid = threadIdx.x;
    const int gp  = tid >> 6;        // gate pair: 0 -> {i,f}, 1 -> {g,o}
    const int j   = tid & 63;        // hidden unit
    const int b   = blockIdx.x >> 1;
    const int dir = blockIdx.x & 1;

    const float* __restrict__ wih = dir ? wih_r : wih_f;
    const float* __restrict__ whh = dir ? whh_r : whh_f;
    const float* __restrict__ bih = dir ? bih_r : bih_f;
    const float* __restrict__ bhh = dir ? bhh_r : bhh_f;

    __shared__ float xs[Tn];         // 2 KB
    __shared__ f32x2 pp[2][2][64];   // [buf][gp][j], 2 KB

    #pragma unroll
    for (int i = 0; i < Tn / 128; ++i)
        xs[i * 128 + tid] = x[(size_t)b * Tn + i * 128 + tid];

    const int r0 = gp * 128 + j;     // row of first gate in pair
    const int r1 = gp * 128 + 64 + j;
    f32x2 w2[64];
    #pragma unroll
    for (int k = 0; k < 64; ++k)
        w2[k] = (f32x2){whh[(size_t)r0 * 64 + k], whh[(size_t)r1 * 64 + k]};
    const f32x2 wx   = {wih[r0], wih[r1]};
    const f32x2 bias = {bih[r0] + bhh[r0], bih[r1] + bhh[r1]};

    __syncthreads();   // once: xs visible (pre-loop drain harmless)

    float h = 0.f, c = 0.f;
    float* __restrict__ outp = h0out + (size_t)b * Tn * 128 + dir * 64 + j;

    for (int s = 0; s < Tn; ++s) {
        const int t  = dir ? (Tn - 1 - s) : s;
        const int bf = s & 1;
        const float xt = xs[t];      // uniform-addr LDS broadcast

        f32x2 p = __builtin_elementwise_fma((f32x2){xt, xt}, wx, bias);
        DOTP(h, p);
        pp[bf][gp][j] = p;
        BAR_LGKM();
        const f32x2 o = pp[bf][1 ^ gp][j];
        ACT_PAIR(p, o, c, h);
        if (gp == 0) outp[(size_t)t * 128] = h;   // wave-uniform; never drained
    }
}

// ---------------------------------------------------------------------------
// Layer 1 forward scan — VERBATIM the Round-3 kernel (measured 638 us):
// (512,2), 2 batch elements x 4 waves, K=192 split 48/wave,
//   wv0: x1a[0:48)  wv1: x1a[48:64)+x1b[0:32)
//   wv2: x1b[32:64)+h[0:16)  wv3: h[16:64)
// Waves 0,1 pure producers w/ 1-step prefetch; waves 2,3 redundantly reduce
// all 4 partials in fixed order + activate. One lgkm-only barrier per step.
// Two elems/block -> two independent reducer-pairs overlap between barriers.
// ---------------------------------------------------------------------------
__global__ __launch_bounds__(512, 2) void k_lstm_l1f(
    const float* __restrict__ h0,
    const float* __restrict__ wih, const float* __restrict__ whh,
    const float* __restrict__ bih, const float* __restrict__ bhh,
    float* __restrict__ h1last)
{
    const int tid = threadIdx.x;
    const int e   = tid >> 8;        // batch element in block
    const int wv  = (tid >> 6) & 3;  // 0..3
    const int j   = tid & 63;
    const int b   = blockIdx.x * 2 + e;
    const int kbase = wv * 48;

    __shared__ float4 part[2][2][4][64];   // [e][buf][wv][unit], 16 KB

    float bias[4];
    #pragma unroll
    for (int g = 0; g < 4; ++g) {
        const int r = g * 64 + j;
        bias[g] = bih[r] + bhh[r];
    }

    float wt[4][48];
    #pragma unroll
    for (int g = 0; g < 4; ++g) {
        const int r = g * 64 + j;
        #pragma unroll
        for (int k4 = 0; k4 < 12; ++k4) {
            const int k = kbase + k4 * 4;
            const float* __restrict__ src = (k < 128)
                ? (wih + (size_t)r * 128 + k)
                : (whh + (size_t)r * 64 + (k - 128));
            const float4 w4 = *reinterpret_cast<const float4*>(src);
            wt[g][k4 * 4 + 0] = w4.x; wt[g][k4 * 4 + 1] = w4.y;
            wt[g][k4 * 4 + 2] = w4.z; wt[g][k4 * 4 + 3] = w4.w;
        }
    }

    const float* __restrict__ xrow = h0 + (size_t)b * Tn * 128;

    float x1a = 0.0f, x1b = 0.0f;
    if (wv <= 1) x1a = xrow[j];
    if (wv == 1 || wv == 2) x1b = xrow[64 + j];
    float h = 0.0f, c = 0.0f;

    for (int t = 0; t < Tn; ++t) {
        const int bf = t & 1;
        const int tn = (t + 1 < Tn) ? (t + 1) : t;
        float nx1a = x1a, nx1b = x1b;
        if (wv <= 1)            nx1a = xrow[(size_t)tn * 128 + j];
        if (wv == 1 || wv == 2) nx1b = xrow[(size_t)tn * 128 + 64 + j];

        float a0 = 0.0f, a1 = 0.0f, a2 = 0.0f, a3 = 0.0f;
        if (wv == 0) {
            #pragma unroll
            for (int kk = 0; kk < 48; ++kk) {
                const float v = rlane(x1a, kk);
                a0 = fmaf(v, wt[0][kk], a0); a1 = fmaf(v, wt[1][kk], a1);
                a2 = fmaf(v, wt[2][kk], a2); a3 = fmaf(v, wt[3][kk], a3);
            }
        } else if (wv == 1) {
            #pragma unroll
            for (int kk = 0; kk < 48; ++kk) {
                const float v = (kk < 16) ? rlane(x1a, 48 + kk) : rlane(x1b, kk - 16);
                a0 = fmaf(v, wt[0][kk], a0); a1 = fmaf(v, wt[1][kk], a1);
                a2 = fmaf(v, wt[2][kk], a2); a3 = fmaf(v, wt[3][kk], a3);
            }
        } else if (wv == 2) {
            #pragma unroll
            for (int kk = 0; kk < 48; ++kk) {
                const float v = (kk < 32) ? rlane(x1b, 32 + kk) : rlane(h, kk - 32);
                a0 = fmaf(v, wt[0][kk], a0); a1 = fmaf(v, wt[1][kk], a1);
                a2 = fmaf(v, wt[2][kk], a2); a3 = fmaf(v, wt[3][kk], a3);
            }
        } else {
            #pragma unroll
            for (int kk = 0; kk < 48; ++kk) {
                const float v = rlane(h, 16 + kk);
                a0 = fmaf(v, wt[0][kk], a0); a1 = fmaf(v, wt[1][kk], a1);
                a2 = fmaf(v, wt[2][kk], a2); a3 = fmaf(v, wt[3][kk], a3);
            }
        }
        part[e][bf][wv][j] = make_float4(a0, a1, a2, a3);
        BAR_LGKM();
        if (wv >= 2) {   // waves 2,3: identical fixed-order reduce + activate
            const float4 q0 = part[e][bf][0][j];
            const float4 q1 = part[e][bf][1][j];
            const float4 q2 = part[e][bf][2][j];
            const float4 q3 = part[e][bf][3][j];
            const float gi = bias[0] + q0.x + q1.x + q2.x + q3.x;
            const float gf = bias[1] + q0.y + q1.y + q2.y + q3.y;
            const float gg = bias[2] + q0.z + q1.z + q2.z + q3.z;
            const float go = bias[3] + q0.w + q1.w + q2.w + q3.w;
            c = sigm(gf) * c + sigm(gi) * tanhf_(gg);
            h = sigm(go) * tanhf_(c);
        }
        x1a = nx1a; x1b = nx1b;
    }
    if (wv == 2) h1last[(size_t)b * 64 + j] = h;
}

// ---------------------------------------------------------------------------
// Layer-1 backward direction collapses to ONE step at t=T-1 (zero init state),
// then the final FC. One wave per batch element.
// ---------------------------------------------------------------------------
__global__ __launch_bounds__(64, 1) void k_l1r_fc(
    const float* __restrict__ h0in,
    const float* __restrict__ wihr,
    const float* __restrict__ bihr, const float* __restrict__ bhhr,
    const float* __restrict__ h1last,
    const float* __restrict__ fcw, const float* __restrict__ fcb,
    float* __restrict__ out)
{
    const int b = blockIdx.x;
    const int j = threadIdx.x;
    const float* __restrict__ xrow = h0in + ((size_t)b * Tn + (Tn - 1)) * 128;
    const float x1a = xrow[j];
    const float x1b = xrow[64 + j];
    float acc[4];
    #pragma unroll
    for (int g = 0; g < 4; ++g) {
        const int r = g * 64 + j;
        float a = bihr[r] + bhhr[r];
        const float* __restrict__ wr = wihr + (size_t)r * 128;
        #pragma unroll
        for (int d4 = 0; d4 < 16; ++d4) {
            const float4 w4 = *reinterpret_cast<const float4*>(&wr[d4 * 4]);
            a = fmaf(rlane(x1a, d4 * 4 + 0), w4.x, a);
            a = fmaf(rlane(x1a, d4 * 4 + 1), w4.y, a);
            a = fmaf(rlane(x1a, d4 * 4 + 2), w4.z, a);
            a = fmaf(rlane(x1a, d4 * 4 + 3), w4.w, a);
        }
        #pragma unroll
        for (int d4 = 0; d4 < 16; ++d4) {
            const float4 w4 = *reinterpret_cast<const float4*>(&wr[64 + d4 * 4]);
            a = fmaf(rlane(x1b, d4 * 4 + 0), w4.x, a);
            a = fmaf(rlane(x1b, d4 * 4 + 1), w4.y, a);
            a = fmaf(rlane(x1b, d4 * 4 + 2), w4.z, a);
            a = fmaf(rlane(x1b, d4 * 4 + 3), w4.w, a);
        }
        acc[g] = a;
    }
    const float cr = sigm(acc[0]) * tanhf_(acc[2]);
    const float hr = sigm(acc[3]) * tanhf_(cr);
    float v = h1last[(size_t)b * 64 + j] * fcw[j] + hr * fcw[64 + j];
    #pragma unroll
    for (int off = 32; off > 0; off >>= 1) v += __shfl_xor(v, off, 64);
    if (j == 0) out[b] = v + fcb[0];
}

// ---------------------------------------------------------------------------
extern "C" void kernel_launch(void* const* d_in, const int* in_sizes, int n_in,
                              void* d_out, int out_size, void* d_ws, size_t ws_size,
                              hipStream_t stream)
{
    const float* x       = (const float*)d_in[0];
    const float* wih_l0  = (const float*)d_in[1];
    const float* whh_l0  = (const float*)d_in[2];
    const float* bih_l0  = (const float*)d_in[3];
    const float* bhh_l0  = (const float*)d_in[4];
    const float* wih_l0r = (const float*)d_in[5];
    const float* whh_l0r = (const float*)d_in[6];
    const float* bih_l0r = (const float*)d_in[7];
    const float* bhh_l0r = (const float*)d_in[8];
    const float* wih_l1  = (const float*)d_in[9];
    const float* whh_l1  = (const float*)d_in[10];
    const float* bih_l1  = (const float*)d_in[11];
    const float* bhh_l1  = (const float*)d_in[12];
    const float* wih_l1r = (const float*)d_in[13];
    const float* whh_l1r = (const float*)d_in[14];
    const float* bih_l1r = (const float*)d_in[15];
    const float* bhh_l1r = (const float*)d_in[16];
    const float* fcw     = (const float*)d_in[17];
    const float* fcb     = (const float*)d_in[18];
    (void)whh_l1r; (void)in_sizes; (void)n_in; (void)out_size; (void)ws_size;

    // ws layout: h0 [512][512][128] f32 (134.2 MB) + h1last [512][64] f32
    float* h0     = (float*)d_ws;
    float* h1last = h0 + (size_t)Bn * Tn * 128;

    k_lstm_l0<<<dim3(Bn * 2), dim3(128), 0, stream>>>(
        x, wih_l0, whh_l0, bih_l0, bhh_l0,
        wih_l0r, whh_l0r, bih_l0r, bhh_l0r, h0);
    k_lstm_l1f<<<dim3(Bn / 2), dim3(512), 0, stream>>>(
        h0, wih_l1, whh_l1, bih_l1, bhh_l1, h1last);
    k_l1r_fc<<<dim3(Bn), dim3(64), 0, stream>>>(
        h0, wih_l1r, bih_l1r, bhh_l1r, h1last, fcw, fcb, (float*)d_out);
}